// Round 2
// baseline (14321.655 us; speedup 1.0000x reference)
//
#include <hip/hip_runtime.h>
#include <cmath>

#define SEQ 512
#define BATCH 2048
#define DIM 64
#define HID 128
#define SB (BATCH * DIM)   // x stride per timestep (floats)

// Round-10: round-9 architecture (256 thr, k-split, LDS-broadcast operands,
// GEMM1(t+1) under GEMM2(t), 2 lgkm-only barriers/step) with the
// global_load_lds DMA replaced by T14 reg-staging (plain global_load_dwordx4
// issued 4 steps early -> ds_write_b128 at the group boundary). r9's bench
// died in-container twice; the DMA builtin was the only exotic suspect, and
// reg-staging costs ~2 extra insts per wave per 4 steps.
//
// Staging schedule (per wave, all 4 waves redundantly stage identical bytes):
//   prologue: load g0,g1 -> write xs[0],xs[1]; issue load g2 into xr
//   t=4g+3:   ds_write xr -> xs[g&1] (group g+2); issue load g+3 into xr
// WAR safe: group g's last read is X(4g+3-4..)/tn<=4g+3 ... all reads of the
// overwritten group complete before B_odd(t-1) < B_even(t-1) < write at top
// of t. RAW safe: my own write drains at B_odd(t) lgkmcnt(0), read 4 steps
// later; other waves' identical-byte writes race benignly.

#define R8(M) M(0) M(1) M(2) M(3) M(4) M(5) M(6) M(7)
#define R16(M) R8(M) M(8) M(9) M(10) M(11) M(12) M(13) M(14) M(15)

#define PIN4(F_) asm volatile("" : "+v"(F_.x), "+v"(F_.y), "+v"(F_.z), "+v"(F_.w));
#define PIN1(F_) asm volatile("" : "+v"(F_));

__device__ __forceinline__ float fast_tanh(float z) {
    // tanh(z) = 1 - 2/(exp(2z)+1); v_exp + v_rcp, exact saturation both ends.
    const float e = __expf(2.0f * z);
    return 1.0f - 2.0f * __builtin_amdgcn_rcpf(e + 1.0f);
}

__global__ __launch_bounds__(256, 4)
void rnn_kernel(const float* __restrict__ x,
                const float* __restrict__ h0,
                const float* __restrict__ W_ih,
                const float* __restrict__ b_ih,
                const float* __restrict__ W_hh,
                const float* __restrict__ b_hh,
                float* __restrict__ out) {
    __shared__ __align__(16) float xs[2][4][64];    // 2 groups x 4 steps x 64 x-vals
    __shared__ __align__(16) float part1[2][HID];   // GEMM1 k-half partials
    __shared__ __align__(16) float part2[2][HID];   // GEMM2 k-half partials
    __shared__ __align__(16) float act[HID];        // wihx broadcast tile

    const int tid = threadIdx.x;
    const int b = blockIdx.x;
    const int j = tid & 127;          // hidden index (two waves per kh-half)
    const int kh = tid >> 7;          // k-half owner: 0 or 1 (wave-uniform)
    const int lane = tid & 63;

    // ---- pinned weight slices: W_ih[j][kh*32 .. +32), W_hh[j][kh*64 .. +64) ----
    const float4* wip = (const float4*)(W_ih + j * DIM + kh * 32);
#define DECL_WI(i) float4 wi##i = wip[i]; PIN4(wi##i)
    R8(DECL_WI)
    const float4* whp = (const float4*)(W_hh + j * HID + kh * 64);
#define DECL_WH(i) float4 wh##i = whp[i]; PIN4(wh##i)
    R16(DECL_WH)

    float bi = b_ih[j];  PIN1(bi)
    float bh = b_hh[j];  PIN1(bh)
    float h = h0[b * HID + j];        // live state on kh==0 threads only

    // ---- x staging: lane L covers step (L>>4), floats (L&15)*4 .. +4 ----
    const float* xgl = x + (size_t)b * DIM + (size_t)(lane >> 4) * SB
                         + (size_t)((lane & 15) * 4);
    float* xlds = &xs[0][lane >> 4][(lane & 15) * 4];  // buffer stride = 256 floats

    float4 xr0 = *(const float4*)(xgl);                    // group 0
    float4 xr1 = *(const float4*)(xgl + 4 * (size_t)SB);   // group 1
    *(float4*)(xlds)       = xr0;   // compiler inserts the vmcnt waits
    *(float4*)(xlds + 256) = xr1;
    float4 xr = *(const float4*)(xgl + 8 * (size_t)SB);    // group 2 in flight
    const float* xnext = xgl + 12 * (size_t)SB;

    // ---- prologue: produce act(0) ----
    float wihx = 0.0f;
    {
        float pP = 0.f, pQ = 0.f;
        const float4* xv = (const float4*)&xs[0][0][kh * 32];
#define G1P(c) { const float4 v_ = xv[c]; \
        pP += wi##c.x * v_.x; pP += wi##c.y * v_.y; \
        pQ += wi##c.z * v_.z; pQ += wi##c.w * v_.w; }
        R8(G1P)
        part1[kh][j] = pP + pQ;
    }
    asm volatile("s_waitcnt lgkmcnt(0)\n\ts_barrier" ::: "memory");
    if (kh == 0) {
        wihx = ((part1[0][j] + part1[1][j]) + bi) * h;
        act[j] = wihx;
    }
    asm volatile("s_waitcnt lgkmcnt(0)\n\ts_barrier" ::: "memory");

#pragma unroll 1
    for (int t = 0; t < SEQ; ++t) {
        // group boundary: commit the in-flight group (t+5..t+8) to LDS and
        // issue the load for the next one. Both guarded by "is it ever read".
        if ((t & 3) == 3) {
            if (t + 5 < SEQ) {
                *(float4*)(xlds + ((t >> 2) & 1) * 256) = xr;  // waits xr's vmcnt
                if (t + 9 < SEQ) {
                    xr = *(const float4*)xnext;
                    xnext += 4 * (size_t)SB;
                }
            }
        }

        // ---- X: GEMM2(t) own k-half + GEMM1(t+1) partial (independent chains) ----
        float qP = 0.f, qQ = 0.f;
        const float4* av = (const float4*)&act[kh * 64];
#define G2P(c) { const float4 v_ = av[c]; \
        qP += wh##c.x * v_.x; qP += wh##c.y * v_.y; \
        qQ += wh##c.z * v_.z; qQ += wh##c.w * v_.w; }
        R16(G2P)

        const int tn = t + 1;
        if (tn < SEQ) {          // GEMM1 is non-recurrent: compute next step's
            float pP = 0.f, pQ = 0.f;  // partials under GEMM2's region
            const float4* xv = (const float4*)&xs[(tn >> 2) & 1][tn & 3][kh * 32];
#define G1N(c) { const float4 v_ = xv[c]; \
            pP += wi##c.x * v_.x; pP += wi##c.y * v_.y; \
            pQ += wi##c.z * v_.z; pQ += wi##c.w * v_.w; }
            R8(G1N)
            part1[kh][j] = pP + pQ;
        }
        part2[kh][j] = qP + qQ;
        asm volatile("s_waitcnt lgkmcnt(0)\n\ts_barrier" ::: "memory");  // B_odd

        // ---- Y: scalar tail on kh==0 waves only ----
        if (kh == 0) {
            const float whh = ((part2[0][j] + part2[1][j]) + bh) * h;
            h = fast_tanh(wihx + whh);
            if (tn < SEQ) {
                wihx = ((part1[0][j] + part1[1][j]) + bi) * h;
                act[j] = wihx;
            }
        }
        asm volatile("s_waitcnt lgkmcnt(0)\n\ts_barrier" ::: "memory");  // B_even
        // act/part single-buffered is safe: read X(t) / write Y(t) split by
        // B_odd; write Y(t) / read X(t+1) split by B_even.
    }

    if (kh == 0) out[b * HID + j] = h;
}

extern "C" void kernel_launch(void* const* d_in, const int* in_sizes, int n_in,
                              void* d_out, int out_size, void* d_ws, size_t ws_size,
                              hipStream_t stream) {
    const float* x    = (const float*)d_in[0];
    const float* h0   = (const float*)d_in[1];
    const float* W_ih = (const float*)d_in[2];
    const float* b_ih = (const float*)d_in[3];
    const float* W_hh = (const float*)d_in[4];
    const float* b_hh = (const float*)d_in[5];
    float* out = (float*)d_out;

    dim3 grid(BATCH);       // one batch element per block
    dim3 block(256);        // 4 waves: (j 0..127) x (k-half 0..1)
    rnn_kernel<<<grid, block, 0, stream>>>(x, h0, W_ih, b_ih, W_hh, b_hh, out);
}

// Round 3
// 5053.081 us; speedup vs baseline: 2.8342x; 2.8342x over previous
//
#include <hip/hip_runtime.h>
#include <cmath>

#define SEQ 512
#define BATCH 2048
#define DIM 64
#define HID 128
#define SB (BATCH * DIM)   // x stride per timestep (floats)

// Round-11: r10 architecture unchanged (256 thr, k-split kh=tid>>7, all
// operand broadcast via wave-uniform ds_read_b128, GEMM1(t+1) interleaved
// under GEMM2(t), 2 lgkm-only barriers/step, reg-staged x -> LDS per 4 steps).
// ONE change: __launch_bounds__(256,3). r10's (256,4) capped VGPRs at 128,
// the ~140-reg demand (96 pinned weights + temps) spilled to scratch, and the
// counters showed the signature: VGPR=64, FETCH=44.9 GB (weights reloaded
// ~20x from scratch), VALUBusy 7.5%. Cap 168 fits demand ~140 with headroom;
// 3 waves/SIMD (vs r8's 2) still nearly doubles effective occupancy.

#define R8(M) M(0) M(1) M(2) M(3) M(4) M(5) M(6) M(7)
#define R16(M) R8(M) M(8) M(9) M(10) M(11) M(12) M(13) M(14) M(15)

#define PIN4(F_) asm volatile("" : "+v"(F_.x), "+v"(F_.y), "+v"(F_.z), "+v"(F_.w));
#define PIN1(F_) asm volatile("" : "+v"(F_));

__device__ __forceinline__ float fast_tanh(float z) {
    // tanh(z) = 1 - 2/(exp(2z)+1); v_exp + v_rcp, exact saturation both ends.
    const float e = __expf(2.0f * z);
    return 1.0f - 2.0f * __builtin_amdgcn_rcpf(e + 1.0f);
}

__global__ __launch_bounds__(256, 3)
void rnn_kernel(const float* __restrict__ x,
                const float* __restrict__ h0,
                const float* __restrict__ W_ih,
                const float* __restrict__ b_ih,
                const float* __restrict__ W_hh,
                const float* __restrict__ b_hh,
                float* __restrict__ out) {
    __shared__ __align__(16) float xs[2][4][64];    // 2 groups x 4 steps x 64 x-vals
    __shared__ __align__(16) float part1[2][HID];   // GEMM1 k-half partials
    __shared__ __align__(16) float part2[2][HID];   // GEMM2 k-half partials
    __shared__ __align__(16) float act[HID];        // wihx broadcast tile

    const int tid = threadIdx.x;
    const int b = blockIdx.x;
    const int j = tid & 127;          // hidden index (two waves per kh-half)
    const int kh = tid >> 7;          // k-half owner: 0 or 1 (wave-uniform)
    const int lane = tid & 63;

    // ---- pinned weight slices: W_ih[j][kh*32 .. +32), W_hh[j][kh*64 .. +64) ----
    const float4* wip = (const float4*)(W_ih + j * DIM + kh * 32);
#define DECL_WI(i) float4 wi##i = wip[i]; PIN4(wi##i)
    R8(DECL_WI)
    const float4* whp = (const float4*)(W_hh + j * HID + kh * 64);
#define DECL_WH(i) float4 wh##i = whp[i]; PIN4(wh##i)
    R16(DECL_WH)

    float bi = b_ih[j];  PIN1(bi)
    float bh = b_hh[j];  PIN1(bh)
    float h = h0[b * HID + j];        // live state on kh==0 threads only

    // ---- x staging: lane L covers step (L>>4), floats (L&15)*4 .. +4 ----
    const float* xgl = x + (size_t)b * DIM + (size_t)(lane >> 4) * SB
                         + (size_t)((lane & 15) * 4);
    float* xlds = &xs[0][lane >> 4][(lane & 15) * 4];  // buffer stride = 256 floats

    *(float4*)(xlds)       = *(const float4*)(xgl);                  // group 0
    *(float4*)(xlds + 256) = *(const float4*)(xgl + 4 * (size_t)SB); // group 1
    float4 xr = *(const float4*)(xgl + 8 * (size_t)SB);  // group 2 in flight
    const float* xnext = xgl + 12 * (size_t)SB;

    // ---- prologue: produce act(0) ----
    float wihx = 0.0f;
    {
        float pP = 0.f, pQ = 0.f;
        const float4* xv = (const float4*)&xs[0][0][kh * 32];
#define G1P(c) { const float4 v_ = xv[c]; \
        pP += wi##c.x * v_.x; pP += wi##c.y * v_.y; \
        pQ += wi##c.z * v_.z; pQ += wi##c.w * v_.w; }
        R8(G1P)
        part1[kh][j] = pP + pQ;
    }
    asm volatile("s_waitcnt lgkmcnt(0)\n\ts_barrier" ::: "memory");
    if (kh == 0) {
        wihx = ((part1[0][j] + part1[1][j]) + bi) * h;
        act[j] = wihx;
    }
    asm volatile("s_waitcnt lgkmcnt(0)\n\ts_barrier" ::: "memory");

#pragma unroll 1
    for (int t = 0; t < SEQ; ++t) {
        // group boundary: commit the in-flight group (covering t+5..t+8) to
        // LDS and issue the load for the next one.
        if ((t & 3) == 3) {
            if (t + 5 < SEQ) {
                *(float4*)(xlds + ((t >> 2) & 1) * 256) = xr;  // waits xr's vmcnt
                if (t + 9 < SEQ) {
                    xr = *(const float4*)xnext;
                    xnext += 4 * (size_t)SB;
                }
            }
        }

        // ---- X: GEMM2(t) own k-half + GEMM1(t+1) partial (independent chains) ----
        float qP = 0.f, qQ = 0.f;
        const float4* av = (const float4*)&act[kh * 64];
#define G2P(c) { const float4 v_ = av[c]; \
        qP += wh##c.x * v_.x; qP += wh##c.y * v_.y; \
        qQ += wh##c.z * v_.z; qQ += wh##c.w * v_.w; }
        R16(G2P)

        const int tn = t + 1;
        if (tn < SEQ) {          // GEMM1 is non-recurrent: compute next step's
            float pP = 0.f, pQ = 0.f;  // partials under GEMM2's region
            const float4* xv = (const float4*)&xs[(tn >> 2) & 1][tn & 3][kh * 32];
#define G1N(c) { const float4 v_ = xv[c]; \
            pP += wi##c.x * v_.x; pP += wi##c.y * v_.y; \
            pQ += wi##c.z * v_.z; pQ += wi##c.w * v_.w; }
            R8(G1N)
            part1[kh][j] = pP + pQ;
        }
        part2[kh][j] = qP + qQ;
        asm volatile("s_waitcnt lgkmcnt(0)\n\ts_barrier" ::: "memory");  // B_odd

        // ---- Y: scalar tail on kh==0 waves only ----
        if (kh == 0) {
            const float whh = ((part2[0][j] + part2[1][j]) + bh) * h;
            h = fast_tanh(wihx + whh);
            if (tn < SEQ) {
                wihx = ((part1[0][j] + part1[1][j]) + bi) * h;
                act[j] = wihx;
            }
        }
        asm volatile("s_waitcnt lgkmcnt(0)\n\ts_barrier" ::: "memory");  // B_even
        // act/part single-buffered is safe: read X(t) / write Y(t) split by
        // B_odd; write Y(t) / read X(t+1) split by B_even.
    }

    if (kh == 0) out[b * HID + j] = h;
}

extern "C" void kernel_launch(void* const* d_in, const int* in_sizes, int n_in,
                              void* d_out, int out_size, void* d_ws, size_t ws_size,
                              hipStream_t stream) {
    const float* x    = (const float*)d_in[0];
    const float* h0   = (const float*)d_in[1];
    const float* W_ih = (const float*)d_in[2];
    const float* b_ih = (const float*)d_in[3];
    const float* W_hh = (const float*)d_in[4];
    const float* b_hh = (const float*)d_in[5];
    float* out = (float*)d_out;

    dim3 grid(BATCH);       // one batch element per block
    dim3 block(256);        // 4 waves: (j 0..127) x (k-half 0..1)
    rnn_kernel<<<grid, block, 0, stream>>>(x, h0, W_ih, b_ih, W_hh, b_hh, out);
}